// Round 13
// baseline (58.118 us; speedup 1.0000x reference)
//
#include <hip/hip_runtime.h>
#include <hip/hip_bf16.h>

#define NB 4
#define NN 512
#define ND 128
#define NH 4
#define NK 32

constexpr float EPSV = 1e-6f;
constexpr float CF   = 2.8853900817779268f;   // 2/ln2
constexpr float L2E  = 1.4426950408889634f;   // log2(e)
constexpr float LN2V = 0.6931471805599453f;   // ln(2)
constexpr float EXPCUT = 25.0f;               // skip terms < e^-25 (rigorous bound)

__device__ __forceinline__ float4 ld4(const float* __restrict__ p) {
  return *reinterpret_cast<const float4*>(p);
}

// Kernel 1: x2 + projections. ai2 row layout (with bias, *CF).
// aj: ajRow (fallback) OR ajT[b][h*32+k][j] (j-contiguous, main path).
// xT[b][d][j] (j-contiguous) for the coalesced gram.
// Block 0 thread 0 computes the rigorous skip threshold dnth.
__global__ __launch_bounds__(256) void dgf_proj(
    const float* __restrict__ x, const float* __restrict__ W1,
    const float* __restrict__ b1, const float* __restrict__ W2,
    const float* __restrict__ b2, float* __restrict__ ai2,
    float* __restrict__ ajRow, float* __restrict__ ajT,
    float* __restrict__ xT, float* __restrict__ x2n,
    float* __restrict__ dnthp) {
  __shared__ float xr[8][ND];
  const int t = threadIdx.x;
  const int blk = blockIdx.x;
  const int b = blk >> 6;
  const int n0 = (blk & 63) << 3;
  const float* xb = x + (size_t)(b * NN + n0) * ND;
  {
    const int row = t >> 5, c = t & 31;
    *reinterpret_cast<float4*>(&xr[row][c * 4]) = ld4(xb + row * ND + c * 4);
  }
  if (blk == 0 && t == 0) {
    // sigma <= softplus(max_h(b2 + sum_k |W2|)); terms with
    // dist > EXPCUT*(2*sigmax^2+eps) are <= e^-EXPCUT -> skippable.
    float m = -1e30f;
    for (int h = 0; h < NH; ++h) {
      float sa = b2[h];
      for (int k = 0; k < NK; ++k) sa += fabsf(W2[h * NK + k]);
      m = fmaxf(m, sa);
    }
    const float e2 = __builtin_amdgcn_exp2f(m * L2E);
    const float lp = __builtin_amdgcn_logf(e2 + 1.f) * LN2V;
    const float sm = (m > 15.f) ? m : lp;          // softplus(m)
    dnthp[0] = -L2E * EXPCUT * fmaf(2.f * sm, sm, EPSV);
  }
  __syncthreads();
  if (t < 8) {
    float s = 0.f;
    for (int d = 0; d < ND; ++d) s = fmaf(xr[t][d], xr[t][d], s);
    x2n[b * NN + n0 + t] = s;
  }
  if (xT) {
#pragma unroll
    for (int w = 0; w < 4; ++w) {
      const int idx = t + w * 256;
      const int d = idx >> 3, row = idx & 7;
      xT[((size_t)b * ND + d) * NN + n0 + row] = xr[row][d];
    }
  }
  const int h = t >> 6, part = (t >> 5) & 1, k = t & 31;
  const float* w1p = W1 + (size_t)(h * 256 + part * 128) * NK + k;
  float acc[8] = {0.f, 0.f, 0.f, 0.f, 0.f, 0.f, 0.f, 0.f};
  for (int d = 0; d < ND; d += 4) {
    const float w0 = w1p[(d + 0) * NK];
    const float w1v = w1p[(d + 1) * NK];
    const float w2v = w1p[(d + 2) * NK];
    const float w3v = w1p[(d + 3) * NK];
#pragma unroll
    for (int row = 0; row < 8; ++row) {
      const float4 xv = *reinterpret_cast<const float4*>(&xr[row][d]);
      float a = acc[row];
      a = fmaf(xv.x, w0, a);
      a = fmaf(xv.y, w1v, a);
      a = fmaf(xv.z, w2v, a);
      a = fmaf(xv.w, w3v, a);
      acc[row] = a;
    }
  }
  if (part == 0) {
    const float bb = b1[h * NK + k];
#pragma unroll
    for (int row = 0; row < 8; ++row) {
      ai2[((size_t)(b * NN + n0 + row) * NH + h) * NK + k] =
          (acc[row] + bb) * CF;
    }
  } else {
    if (ajT) {
#pragma unroll
      for (int row = 0; row < 8; ++row) {
        ajT[((size_t)(b * 128 + h * NK + k)) * NN + n0 + row] = acc[row] * CF;
      }
    } else {
#pragma unroll
      for (int row = 0; row < 8; ++row) {
        ajRow[((size_t)(b * NN + n0 + row) * NH + h) * NK + k] = acc[row] * CF;
      }
    }
  }
}

// Kernel 2: fully fused, all loads coalesced or LDS-staged.
// B1 gram via xT (coalesced scalar), B2 heads via ajT (coalesced, wave-skip),
// C adj@x via LDS-staged 64-row x chunks, D proj.
// grid = 512, 512 thr; XCD-pinned: xcd=blk&7 -> b=xcd>>1, hi=xcd&1.
__global__ __launch_bounds__(512, 4) void dgf_adj3(
    const float* __restrict__ x, const float* __restrict__ W2,
    const float* __restrict__ b2, const float* __restrict__ Wp,
    const float* __restrict__ bp, const float* __restrict__ ai2,
    const float* __restrict__ ajT, const float* __restrict__ xT,
    const float* __restrict__ x2n, const float* __restrict__ dnthp,
    float* __restrict__ out) {
  __shared__ float4 xis4[128];       // xi transposed: [d] -> (r0..r3)  2KB
  __shared__ float4 ai2s4[4 * 32];   // 2KB
  __shared__ float4 w2s4[32];        // -2*W2
  __shared__ float x2is[4];
  __shared__ float b2s[4];           // b2[h] + sum_k W2[h][k]
  __shared__ float dnths;
  __shared__ float4 adjs4[512];      // [j] -> (r0..r3)  8KB
  __shared__ float4 sbuf4[2048];     // 32KB: x-chunk stage -> partials -> pd
  __shared__ float hsT[4 * 128];     // 2KB
  const int t = threadIdx.x;
  const int blk = blockIdx.x;
  const int xcd = blk & 7;
  const int b = xcd >> 1;
  const int i0 = (((xcd & 1) << 6) + (blk >> 3)) << 2;

  // ---- Phase A: stage ----
  if (t < 128) {
    const int r = t >> 5, c = t & 31;
    const float4 v = ld4(x + (size_t)(b * NN + i0 + r) * ND + c * 4);
    float* xisf = reinterpret_cast<float*>(xis4);
    xisf[(4 * c + 0) * 4 + r] = v.x;
    xisf[(4 * c + 1) * 4 + r] = v.y;
    xisf[(4 * c + 2) * 4 + r] = v.z;
    xisf[(4 * c + 3) * 4 + r] = v.w;
    ai2s4[t] = ld4(ai2 + (size_t)(b * NN + i0 + r) * (NH * NK) + c * 4);
  } else if (t < 160) {
    const float4 w = ld4(W2 + (t - 128) * 4);
    float4 wn;
    wn.x = -2.f * w.x; wn.y = -2.f * w.y; wn.z = -2.f * w.z; wn.w = -2.f * w.w;
    w2s4[t - 128] = wn;
  } else if (t < 164) {
    const int h = t - 160;
    float sw = 0.f;
    for (int k = 0; k < NK; ++k) sw += W2[h * NK + k];
    b2s[h] = b2[h] + sw;
    x2is[h] = x2n[b * NN + i0 + h];
  } else if (t == 164) {
    dnths = dnthp[0];
  }
  __syncthreads();

  // ---- B1: gram via transposed x (coalesced: lane = j) ----
  float dn[4];
  {
    float g[4] = {0.f, 0.f, 0.f, 0.f};
    const float* xTb = xT + (size_t)b * ND * NN + t;
#pragma unroll 8
    for (int d = 0; d < ND; ++d) {
      const float xv = xTb[(size_t)d * NN];
      const float4 xi = xis4[d];
      g[0] = fmaf(xi.x, xv, g[0]);
      g[1] = fmaf(xi.y, xv, g[1]);
      g[2] = fmaf(xi.z, xv, g[2]);
      g[3] = fmaf(xi.w, xv, g[3]);
    }
    const float x2j = x2n[b * NN + t];
#pragma unroll
    for (int r = 0; r < 4; ++r)
      dn[r] = -L2E * fmaxf(x2is[r] + x2j - 2.f * g[r], 0.f);
  }

  // ---- B2 (wave-skippable): sum_k w*tanh = sum_k w + sum_k (-2w)*sigmoid ----
  float adjv[4] = {0.f, 0.f, 0.f, 0.f};
  {
    const float dnth = dnths;
    const bool need = (dn[0] > dnth) || (dn[1] > dnth) ||
                      (dn[2] > dnth) || (dn[3] > dnth);
    if (__any(need)) {
      const float* ajTb = ajT + (size_t)b * 128 * NN + t;
      for (int h = 0; h < NH; ++h) {
        float s[4] = {0.f, 0.f, 0.f, 0.f};
#pragma unroll
        for (int kc = 0; kc < 8; ++kc) {
          const float4 w2c = w2s4[h * 8 + kc];   // already -2*W2
          const int hk = h * NK + kc * 4;
          const float a0 = ajTb[(size_t)(hk + 0) * NN];
          const float a1 = ajTb[(size_t)(hk + 1) * NN];
          const float a2 = ajTb[(size_t)(hk + 2) * NN];
          const float a3 = ajTb[(size_t)(hk + 3) * NN];
#pragma unroll
          for (int r = 0; r < 4; ++r) {
            const float4 ac = ai2s4[r * 32 + h * 8 + kc];
            float z, rc, sr = s[r];
            z = ac.x + a0;
            rc = __builtin_amdgcn_rcpf(__builtin_amdgcn_exp2f(z) + 1.f);
            sr = fmaf(w2c.x, rc, sr);
            z = ac.y + a1;
            rc = __builtin_amdgcn_rcpf(__builtin_amdgcn_exp2f(z) + 1.f);
            sr = fmaf(w2c.y, rc, sr);
            z = ac.z + a2;
            rc = __builtin_amdgcn_rcpf(__builtin_amdgcn_exp2f(z) + 1.f);
            sr = fmaf(w2c.z, rc, sr);
            z = ac.w + a3;
            rc = __builtin_amdgcn_rcpf(__builtin_amdgcn_exp2f(z) + 1.f);
            sr = fmaf(w2c.w, rc, sr);
            s[r] = sr;
          }
        }
#pragma unroll
        for (int r = 0; r < 4; ++r) {
          const float si = s[r] + b2s[h];       // + (b2 + sum_k W2)
          const float e2 = __builtin_amdgcn_exp2f(si * L2E);
          const float lp = __builtin_amdgcn_logf(e2 + 1.f) * LN2V;
          const float sp = (si > 15.f) ? si : lp;   // softplus
          const float den = fmaf(2.f * sp, sp, EPSV);
          const float rr = __builtin_amdgcn_rcpf(den);
          adjv[r] += __builtin_amdgcn_exp2f(dn[r] * rr);
        }
      }
    }
  }
  {
    float4 v;
    v.x = adjv[0] * 0.25f; v.y = adjv[1] * 0.25f;
    v.z = adjv[2] * 0.25f; v.w = adjv[3] * 0.25f;
    adjs4[t] = v;
  }

  // ---- Phase C: h_out = adj @ x, x LDS-staged in 64-row chunks ----
  float4 f0 = {0,0,0,0}, f1 = {0,0,0,0}, f2 = {0,0,0,0}, f3 = {0,0,0,0};
  {
    const int dg = t & 31, g = t >> 5;   // 16 groups; group g: 4 j per chunk
    const float4* xb4 =
        reinterpret_cast<const float4*>(x + (size_t)(b * NN) * ND);
    for (int c = 0; c < 8; ++c) {
      __syncthreads();   // also covers the adjs4 write before c=0
#pragma unroll
      for (int k = 0; k < 4; ++k)
        sbuf4[k * 512 + t] = xb4[(size_t)c * 2048 + k * 512 + t];
      __syncthreads();
#pragma unroll
      for (int v = 0; v < 4; ++v) {
        const int jl = g * 4 + v;                 // 0..63 within chunk
        const float4 a = adjs4[c * 64 + jl];
        const float4 xv = sbuf4[jl * 32 + dg];
        f0.x = fmaf(a.x, xv.x, f0.x); f0.y = fmaf(a.x, xv.y, f0.y);
        f0.z = fmaf(a.x, xv.z, f0.z); f0.w = fmaf(a.x, xv.w, f0.w);
        f1.x = fmaf(a.y, xv.x, f1.x); f1.y = fmaf(a.y, xv.y, f1.y);
        f1.z = fmaf(a.y, xv.z, f1.z); f1.w = fmaf(a.y, xv.w, f1.w);
        f2.x = fmaf(a.z, xv.x, f2.x); f2.y = fmaf(a.z, xv.y, f2.y);
        f2.z = fmaf(a.z, xv.z, f2.z); f2.w = fmaf(a.z, xv.w, f2.w);
        f3.x = fmaf(a.w, xv.x, f3.x); f3.y = fmaf(a.w, xv.y, f3.y);
        f3.z = fmaf(a.w, xv.z, f3.z); f3.w = fmaf(a.w, xv.w, f3.w);
      }
    }
  }
  __syncthreads();   // last chunk fully read; sbuf reusable as partials
  {
    const int dg = t & 31, g = t >> 5;
    sbuf4[g * 128 + 0 * 32 + dg] = f0;   // pc[g*512 + r*128 + dg*4..]
    sbuf4[g * 128 + 1 * 32 + dg] = f1;
    sbuf4[g * 128 + 2 * 32 + dg] = f2;
    sbuf4[g * 128 + 3 * 32 + dg] = f3;
  }
  __syncthreads();
  {
    const float* pc = reinterpret_cast<const float*>(sbuf4);
    float v = 0.f;
#pragma unroll
    for (int g = 0; g < 16; ++g) v += pc[g * 512 + t];
    hsT[t] = v;   // t = r*128 + e
  }
  __syncthreads();

  // ---- Phase D: out = h_out @ Wp + bp ----
  {
    const int d = t & 127, eh = t >> 7;
    float a0 = 0.f, a1 = 0.f, a2 = 0.f, a3 = 0.f;
    for (int ee = 0; ee < 32; ++ee) {
      const int e = eh * 32 + ee;
      const float w = Wp[(size_t)e * ND + d];
      a0 = fmaf(hsT[0 * 128 + e], w, a0);
      a1 = fmaf(hsT[1 * 128 + e], w, a1);
      a2 = fmaf(hsT[2 * 128 + e], w, a2);
      a3 = fmaf(hsT[3 * 128 + e], w, a3);
    }
    float* pd = reinterpret_cast<float*>(sbuf4);
    pd[eh * 512 + 0 * 128 + d] = a0;
    pd[eh * 512 + 1 * 128 + d] = a1;
    pd[eh * 512 + 2 * 128 + d] = a2;
    pd[eh * 512 + 3 * 128 + d] = a3;
  }
  __syncthreads();
  {
    const float* pd = reinterpret_cast<const float*>(sbuf4);
    const int r = t >> 7, d = t & 127;
    const float v = pd[0 * 512 + t] + pd[1 * 512 + t] + pd[2 * 512 + t] +
                    pd[3 * 512 + t] + bp[d];
    out[(size_t)(b * NN + i0 + r) * ND + d] = v;
  }
}

// Fallback: fused kernel (R3-verified, row layouts), used if ws is too small.
__global__ __launch_bounds__(512, 4) void dgf_fused(
    const float* __restrict__ x, const float* __restrict__ W2,
    const float* __restrict__ b2, const float* __restrict__ Wp,
    const float* __restrict__ bp, const float* __restrict__ ai2,
    const float* __restrict__ aj2, const float* __restrict__ x2n,
    float* __restrict__ out) {
  __shared__ float4 xi4[4 * 32];
  __shared__ float4 ai2s4[4 * 32];
  __shared__ float4 w2s4[32];
  __shared__ float x2is[4];
  __shared__ float b2s[4];
  __shared__ float4 adjs4[512];
  __shared__ float pcbuf[16 * 512];
  __shared__ float hsT[4 * 128];
  const int t = threadIdx.x;
  const int blk = blockIdx.x;
  const int b = blk >> 7;
  const int i0 = (blk & 127) << 2;

  if (t < 128) {
    const int r = t >> 5;
    const int c = t & 31;
    xi4[t]   = ld4(x   + (size_t)(b * NN + i0 + r) * ND + c * 4);
    ai2s4[t] = ld4(ai2 + (size_t)(b * NN + i0 + r) * (NH * NK) + c * 4);
  } else if (t < 160) {
    const float4 w = ld4(W2 + (t - 128) * 4);
    float4 wn;
    wn.x = -2.f * w.x; wn.y = -2.f * w.y; wn.z = -2.f * w.z; wn.w = -2.f * w.w;
    w2s4[t - 128] = wn;
  } else if (t < 164) {
    x2is[t - 160] = x2n[b * NN + i0 + (t - 160)];
  } else if (t < 168) {
    const int h = t - 164;
    float sw = 0.f;
    for (int k = 0; k < NK; ++k) sw += W2[h * NK + k];
    b2s[h] = b2[h] + sw;
  }
  __syncthreads();

  float dn[4];
  {
    float g[4] = {0.f, 0.f, 0.f, 0.f};
    const float* xj = x + (size_t)(b * NN + t) * ND;
    for (int c = 0; c < 32; ++c) {
      const float4 a = ld4(xj + c * 4);
#pragma unroll
      for (int r = 0; r < 4; ++r) {
        const float4 xv = xi4[r * 32 + c];
        float u = g[r];
        u = fmaf(xv.x, a.x, u); u = fmaf(xv.y, a.y, u);
        u = fmaf(xv.z, a.z, u); u = fmaf(xv.w, a.w, u);
        g[r] = u;
      }
    }
    const float x2j = x2n[b * NN + t];
#pragma unroll
    for (int r = 0; r < 4; ++r)
      dn[r] = -L2E * fmaxf(x2is[r] + x2j - 2.f * g[r], 0.f);
  }

  float adjv[4] = {0.f, 0.f, 0.f, 0.f};
  {
    const float* ajp = aj2 + (size_t)(b * NN + t) * (NH * NK);
    for (int h = 0; h < NH; ++h) {
      float4 aj[8];
#pragma unroll
      for (int c = 0; c < 8; ++c) aj[c] = ld4(ajp + h * NK + c * 4);
      float s[4] = {0.f, 0.f, 0.f, 0.f};
#pragma unroll
      for (int kc = 0; kc < 8; ++kc) {
        const float4 w2c = w2s4[h * 8 + kc];
        const float4 ajc = aj[kc];
#pragma unroll
        for (int r = 0; r < 4; ++r) {
          const float4 ac = ai2s4[r * 32 + h * 8 + kc];
          float z, rc, sr = s[r];
          z = ac.x + ajc.x;
          rc = __builtin_amdgcn_rcpf(__builtin_amdgcn_exp2f(z) + 1.f);
          sr = fmaf(w2c.x, rc, sr);
          z = ac.y + ajc.y;
          rc = __builtin_amdgcn_rcpf(__builtin_amdgcn_exp2f(z) + 1.f);
          sr = fmaf(w2c.y, rc, sr);
          z = ac.z + ajc.z;
          rc = __builtin_amdgcn_rcpf(__builtin_amdgcn_exp2f(z) + 1.f);
          sr = fmaf(w2c.z, rc, sr);
          z = ac.w + ajc.w;
          rc = __builtin_amdgcn_rcpf(__builtin_amdgcn_exp2f(z) + 1.f);
          sr = fmaf(w2c.w, rc, sr);
          s[r] = sr;
        }
      }
#pragma unroll
      for (int r = 0; r < 4; ++r) {
        const float si = s[r] + b2s[h];
        const float e2 = __builtin_amdgcn_exp2f(si * L2E);
        const float lp = __builtin_amdgcn_logf(e2 + 1.f) * LN2V;
        const float sp = (si > 15.f) ? si : lp;
        const float den = fmaf(2.f * sp, sp, EPSV);
        const float rr = __builtin_amdgcn_rcpf(den);
        adjv[r] += __builtin_amdgcn_exp2f(dn[r] * rr);
      }
    }
  }
  {
    float4 v;
    v.x = adjv[0] * 0.25f; v.y = adjv[1] * 0.25f;
    v.z = adjv[2] * 0.25f; v.w = adjv[3] * 0.25f;
    adjs4[t] = v;
  }
  __syncthreads();

  {
    const int dg = t & 31, jp = t >> 5;
    float4 f0 = {0,0,0,0}, f1 = {0,0,0,0}, f2 = {0,0,0,0}, f3 = {0,0,0,0};
    const float* xb = x + (size_t)(b * NN) * ND;
    for (int u = 0; u < 32; ++u) {
      const int j = jp * 32 + u;
      const float4 a = adjs4[j];
      const float4 xv = ld4(xb + (size_t)j * ND + dg * 4);
      f0.x = fmaf(a.x, xv.x, f0.x); f0.y = fmaf(a.x, xv.y, f0.y);
      f0.z = fmaf(a.x, xv.z, f0.z); f0.w = fmaf(a.x, xv.w, f0.w);
      f1.x = fmaf(a.y, xv.x, f1.x); f1.y = fmaf(a.y, xv.y, f1.y);
      f1.z = fmaf(a.y, xv.z, f1.z); f1.w = fmaf(a.y, xv.w, f1.w);
      f2.x = fmaf(a.z, xv.x, f2.x); f2.y = fmaf(a.z, xv.y, f2.y);
      f2.z = fmaf(a.z, xv.z, f2.z); f2.w = fmaf(a.z, xv.w, f2.w);
      f3.x = fmaf(a.w, xv.x, f3.x); f3.y = fmaf(a.w, xv.y, f3.y);
      f3.z = fmaf(a.w, xv.z, f3.z); f3.w = fmaf(a.w, xv.w, f3.w);
    }
    float4* pc4 = reinterpret_cast<float4*>(pcbuf);
    pc4[jp * 128 + 0 * 32 + dg] = f0;
    pc4[jp * 128 + 1 * 32 + dg] = f1;
    pc4[jp * 128 + 2 * 32 + dg] = f2;
    pc4[jp * 128 + 3 * 32 + dg] = f3;
  }
  __syncthreads();
  {
    float v = 0.f;
#pragma unroll
    for (int jp = 0; jp < 16; ++jp) v += pcbuf[jp * 512 + t];
    hsT[t] = v;
  }
  __syncthreads();
  {
    const int d = t & 127, eh = t >> 7;
    float a0 = 0.f, a1 = 0.f, a2 = 0.f, a3 = 0.f;
    for (int ee = 0; ee < 32; ++ee) {
      const int e = eh * 32 + ee;
      const float w = Wp[(size_t)e * ND + d];
      a0 = fmaf(hsT[0 * 128 + e], w, a0);
      a1 = fmaf(hsT[1 * 128 + e], w, a1);
      a2 = fmaf(hsT[2 * 128 + e], w, a2);
      a3 = fmaf(hsT[3 * 128 + e], w, a3);
    }
    float* pd = pcbuf;
    pd[eh * 512 + 0 * 128 + d] = a0;
    pd[eh * 512 + 1 * 128 + d] = a1;
    pd[eh * 512 + 2 * 128 + d] = a2;
    pd[eh * 512 + 3 * 128 + d] = a3;
  }
  __syncthreads();
  {
    const int d = t & 127;
    const float v = pcbuf[0 * 512 + t] + pcbuf[1 * 512 + t] +
                    pcbuf[2 * 512 + t] + pcbuf[3 * 512 + t] + bp[d];
    const int r = t >> 7;
    out[(size_t)(b * NN + i0 + r) * ND + d] = v;
  }
}

extern "C" void kernel_launch(void* const* d_in, const int* in_sizes, int n_in,
                              void* d_out, int out_size, void* d_ws, size_t ws_size,
                              hipStream_t stream) {
  const float* x  = (const float*)d_in[0];
  const float* W1 = (const float*)d_in[1];
  const float* b1 = (const float*)d_in[2];
  const float* W2 = (const float*)d_in[3];
  const float* b2 = (const float*)d_in[4];
  const float* Wp = (const float*)d_in[5];
  const float* bp = (const float*)d_in[6];
  float* out = (float*)d_out;

  const size_t nProj = (size_t)NB * NN * NH * NK;   // 262144
  const size_t nX2   = (size_t)NB * NN;             // 2048
  const size_t nT    = (size_t)NB * ND * NN;        // 262144 (ajT, xT each)

  float* aj2 = (float*)d_ws;        // row-layout slot (fallback path)
  float* ai2 = aj2 + nProj;
  float* x2n = ai2 + nProj;
  float* dnt = x2n + nX2;           // 4 floats (1 used)
  float* ajT = dnt + 4;
  float* xT  = ajT + nT;

  const bool big = ws_size >= (2 * nProj + nX2 + 4 + 2 * nT) * sizeof(float);

  dgf_proj<<<NB * NN / 8, 256, 0, stream>>>(
      x, W1, b1, W2, b2, ai2, big ? nullptr : aj2, big ? ajT : nullptr,
      big ? xT : nullptr, x2n, dnt);

  if (big) {
    dgf_adj3<<<NB * (NN / 4), 512, 0, stream>>>(x, W2, b2, Wp, bp, ai2, ajT,
                                                xT, x2n, dnt, out);
  } else {
    dgf_fused<<<NB * (NN / 4), 512, 0, stream>>>(x, W2, b2, Wp, bp, ai2, aj2,
                                                 x2n, out);
  }
}

// Round 14
// 52.067 us; speedup vs baseline: 1.1162x; 1.1162x over previous
//
#include <hip/hip_runtime.h>
#include <hip/hip_bf16.h>

#define NB 4
#define NN 512
#define ND 128
#define NH 4
#define NK 32

constexpr float EPSV = 1e-6f;
constexpr float CF   = 2.8853900817779268f;   // 2/ln2
constexpr float L2E  = 1.4426950408889634f;   // log2(e)
constexpr float LN2V = 0.6931471805599453f;   // ln(2)
constexpr float EXPCUT = 25.0f;               // skip terms < e^-25 (rigorous bound)

__device__ __forceinline__ float4 ld4(const float* __restrict__ p) {
  return *reinterpret_cast<const float4*>(p);
}

// Kernel 1: x2 + projections ai' = (x@W1a + b1)*CF, aj' = (x@W1b)*CF.
// Block 0 thread 0 computes the rigorous skip threshold dnth.
__global__ __launch_bounds__(256) void dgf_proj(
    const float* __restrict__ x, const float* __restrict__ W1,
    const float* __restrict__ b1, const float* __restrict__ W2,
    const float* __restrict__ b2, float* __restrict__ ai2,
    float* __restrict__ aj2, float* __restrict__ x2n,
    float* __restrict__ dnthp) {
  __shared__ float xr[8][ND];
  const int t = threadIdx.x;
  const int blk = blockIdx.x;
  const int b = blk >> 6;
  const int n0 = (blk & 63) << 3;
  const float* xb = x + (size_t)(b * NN + n0) * ND;
  {
    const int row = t >> 5, c = t & 31;
    *reinterpret_cast<float4*>(&xr[row][c * 4]) = ld4(xb + row * ND + c * 4);
  }
  if (blk == 0 && t == 0) {
    // sigma <= softplus(max_h(b2 + sum_k |W2|)); terms with
    // dist > EXPCUT*(2*sigmax^2+eps) are <= e^-EXPCUT -> skippable.
    float m = -1e30f;
    for (int h = 0; h < NH; ++h) {
      float sa = b2[h];
      for (int k = 0; k < NK; ++k) sa += fabsf(W2[h * NK + k]);
      m = fmaxf(m, sa);
    }
    const float e2 = __builtin_amdgcn_exp2f(m * L2E);
    const float lp = __builtin_amdgcn_logf(e2 + 1.f) * LN2V;
    const float sm = (m > 15.f) ? m : lp;          // softplus(m)
    dnthp[0] = -L2E * EXPCUT * fmaf(2.f * sm, sm, EPSV);
  }
  __syncthreads();
  if (t < 8) {
    float s = 0.f;
    for (int d = 0; d < ND; ++d) s = fmaf(xr[t][d], xr[t][d], s);
    x2n[b * NN + n0 + t] = s;
  }
  const int h = t >> 6, part = (t >> 5) & 1, k = t & 31;
  const float* w1p = W1 + (size_t)(h * 256 + part * 128) * NK + k;
  float acc[8] = {0.f, 0.f, 0.f, 0.f, 0.f, 0.f, 0.f, 0.f};
  for (int d = 0; d < ND; d += 4) {
    const float w0 = w1p[(d + 0) * NK];
    const float w1v = w1p[(d + 1) * NK];
    const float w2v = w1p[(d + 2) * NK];
    const float w3v = w1p[(d + 3) * NK];
#pragma unroll
    for (int row = 0; row < 8; ++row) {
      const float4 xv = *reinterpret_cast<const float4*>(&xr[row][d]);
      float a = acc[row];
      a = fmaf(xv.x, w0, a);
      a = fmaf(xv.y, w1v, a);
      a = fmaf(xv.z, w2v, a);
      a = fmaf(xv.w, w3v, a);
      acc[row] = a;
    }
  }
  const float bb = (part == 0) ? b1[h * NK + k] : 0.f;
  float* outp = (part == 0) ? ai2 : aj2;
#pragma unroll
  for (int row = 0; row < 8; ++row) {
    outp[((size_t)(b * NN + n0 + row) * NH + h) * NK + k] = (acc[row] + bb) * CF;
  }
}

// Kernel 1b: distn[b][i][j] = -L2E * max(x2i + x2j - 2*<xi,xj>, 0)
// grid=512, XCD-pinned: xcd=blk&7 -> b=xcd>>1, hi=xcd&1.
__global__ __launch_bounds__(256) void dgf_dist(
    const float* __restrict__ x, const float* __restrict__ x2n,
    float* __restrict__ distn) {
  __shared__ float4 xi4s[8 * 32];   // 8 i-rows   4KB
  __shared__ float x2is[8];
  const int t = threadIdx.x;
  const int blk = blockIdx.x;
  const int xcd = blk & 7;
  const int idx = blk >> 3;
  const int b = xcd >> 1;
  const int igrp = ((xcd & 1) << 5) + (idx >> 1);
  const int jh = idx & 1;
  const int i0 = igrp << 3;
  const int j = (jh << 8) + t;

  {
    const int row = t >> 5, c = t & 31;
    xi4s[t] = ld4(x + (size_t)(b * NN + i0 + row) * ND + c * 4);
  }
  if (t < 8) x2is[t] = x2n[b * NN + i0 + t];
  __syncthreads();

  float g[8] = {0.f, 0.f, 0.f, 0.f, 0.f, 0.f, 0.f, 0.f};
  const float* xj = x + (size_t)(b * NN + j) * ND;
  for (int c = 0; c < 32; ++c) {
    const float4 a = ld4(xj + c * 4);
#pragma unroll
    for (int r = 0; r < 8; ++r) {
      const float4 xv = xi4s[r * 32 + c];
      float u = g[r];
      u = fmaf(xv.x, a.x, u); u = fmaf(xv.y, a.y, u);
      u = fmaf(xv.z, a.z, u); u = fmaf(xv.w, a.w, u);
      g[r] = u;
    }
  }
  const float x2j = x2n[b * NN + j];
  float* dp = distn + (size_t)b * NN * NN + (size_t)i0 * NN + j;
#pragma unroll
  for (int r = 0; r < 8; ++r) {
    dp[(size_t)r * NN] = -L2E * fmaxf(x2is[r] + x2j - 2.f * g[r], 0.f);
  }
}

// Kernel 2: B2 (heads, wave-skip) + C (adj@x) + D (proj), dist precomputed.
// i-tile = 2 -> grid = B*(N/2) = 1024 blocks = 4 blocks/CU (2x the TLP of
// the R12 version; safe now because the gram lives in dgf_dist, so the only
// duplicated traffic is Phase C's L2-resident x-stream).
// XCD-pinned: xcd=blk&7 -> b=xcd>>1, hi=xcd&1; i0 = ((hi<<7)+(blk>>3))<<1.
__global__ __launch_bounds__(512, 4) void dgf_adj(
    const float* __restrict__ x, const float* __restrict__ W2,
    const float* __restrict__ b2, const float* __restrict__ Wp,
    const float* __restrict__ bp, const float* __restrict__ ai2,
    const float* __restrict__ aj2, const float* __restrict__ distn,
    float* __restrict__ out) {
  __shared__ float4 ai2s4[2 * 32];   // 2 i-rows of ai'  1KB
  __shared__ float4 w2s4[32];        // -2*W2 [h][k]     0.5KB
  __shared__ float b2s[4];           // b2[h] + sum_k W2[h][k]
  __shared__ float dnths;            // skip threshold in dn units
  __shared__ float2 adjs2[512];      // [j] -> (r0, r1)  4KB
  __shared__ float pcbuf[16 * 256];  // 16KB: C partials; reused as pd in D
  __shared__ float hsT[2 * 128];     // [r][e]  1KB
  const int t = threadIdx.x;
  const int blk = blockIdx.x;
  const int xcd = blk & 7;
  const int b = xcd >> 1;
  const int i0 = (((xcd & 1) << 7) + (blk >> 3)) << 1;

  // ---- Phase A ----
  if (t < 64) {
    const int r = t >> 5;
    const int c = t & 31;
    ai2s4[t] = ld4(ai2 + (size_t)(b * NN + i0 + r) * (NH * NK) + c * 4);
  } else if (t < 96) {
    const float4 w = ld4(W2 + (t - 64) * 4);
    float4 wn;
    wn.x = -2.f * w.x; wn.y = -2.f * w.y; wn.z = -2.f * w.z; wn.w = -2.f * w.w;
    w2s4[t - 64] = wn;
  } else if (t < 100) {
    const int h = t - 96;
    float sw = 0.f;
    for (int k = 0; k < NK; ++k) sw += W2[h * NK + k];
    b2s[h] = b2[h] + sw;
  } else if (t == 100) {
    float m = -1e30f;
    for (int h = 0; h < NH; ++h) {
      float sa = b2[h];
      for (int k = 0; k < NK; ++k) sa += fabsf(W2[h * NK + k]);
      m = fmaxf(m, sa);
    }
    const float e2 = __builtin_amdgcn_exp2f(m * L2E);
    const float lp = __builtin_amdgcn_logf(e2 + 1.f) * LN2V;
    const float sm = (m > 15.f) ? m : lp;          // softplus(m)
    dnths = -L2E * EXPCUT * fmaf(2.f * sm, sm, EPSV);
  }
  __syncthreads();

  // ---- distn loads ----
  float dn[2];
  {
    const float* dp = distn + (size_t)b * NN * NN + (size_t)i0 * NN + t;
    dn[0] = dp[0];
    dn[1] = dp[NN];
  }

  // ---- Phase B2 (wave-skippable): sum_k w*tanh = sum_k w + sum_k (-2w)*sigmoid ----
  float adjv[2] = {0.f, 0.f};
  {
    const float dnth = dnths;
    const bool need = (dn[0] > dnth) || (dn[1] > dnth);
    if (__any(need)) {
      const float* ajp = aj2 + (size_t)(b * NN + t) * (NH * NK);
      for (int h = 0; h < NH; ++h) {
        float4 aj[8];
#pragma unroll
        for (int c = 0; c < 8; ++c) aj[c] = ld4(ajp + h * NK + c * 4);
        float s[2] = {0.f, 0.f};
#pragma unroll
        for (int kc = 0; kc < 8; ++kc) {
          const float4 w2c = w2s4[h * 8 + kc];   // already -2*W2
          const float4 ajc = aj[kc];
#pragma unroll
          for (int r = 0; r < 2; ++r) {
            const float4 ac = ai2s4[r * 32 + h * 8 + kc];
            float z, rc, sr = s[r];
            z = ac.x + ajc.x;
            rc = __builtin_amdgcn_rcpf(__builtin_amdgcn_exp2f(z) + 1.f);
            sr = fmaf(w2c.x, rc, sr);
            z = ac.y + ajc.y;
            rc = __builtin_amdgcn_rcpf(__builtin_amdgcn_exp2f(z) + 1.f);
            sr = fmaf(w2c.y, rc, sr);
            z = ac.z + ajc.z;
            rc = __builtin_amdgcn_rcpf(__builtin_amdgcn_exp2f(z) + 1.f);
            sr = fmaf(w2c.z, rc, sr);
            z = ac.w + ajc.w;
            rc = __builtin_amdgcn_rcpf(__builtin_amdgcn_exp2f(z) + 1.f);
            sr = fmaf(w2c.w, rc, sr);
            s[r] = sr;
          }
        }
#pragma unroll
        for (int r = 0; r < 2; ++r) {
          const float si = s[r] + b2s[h];       // + (b2 + sum_k W2)
          const float e2 = __builtin_amdgcn_exp2f(si * L2E);
          const float lp = __builtin_amdgcn_logf(e2 + 1.f) * LN2V;
          const float sp = (si > 15.f) ? si : lp;   // softplus
          const float den = fmaf(2.f * sp, sp, EPSV);
          const float rr = __builtin_amdgcn_rcpf(den);
          adjv[r] += __builtin_amdgcn_exp2f(dn[r] * rr);
        }
      }
    }
  }
  {
    float2 v;
    v.x = adjv[0] * 0.25f;
    v.y = adjv[1] * 0.25f;
    adjs2[t] = v;
  }
  __syncthreads();

  // ---- Phase C: h_out = adj @ x ----
  {
    const int dg = t & 31, jp = t >> 5;   // 16 j-groups of 32 j's
    float4 f0 = {0,0,0,0}, f1 = {0,0,0,0};
    const float* xb = x + (size_t)(b * NN) * ND;
    for (int u = 0; u < 32; ++u) {
      const int j = jp * 32 + u;
      const float2 a = adjs2[j];
      const float4 xv = ld4(xb + (size_t)j * ND + dg * 4);
      f0.x = fmaf(a.x, xv.x, f0.x); f0.y = fmaf(a.x, xv.y, f0.y);
      f0.z = fmaf(a.x, xv.z, f0.z); f0.w = fmaf(a.x, xv.w, f0.w);
      f1.x = fmaf(a.y, xv.x, f1.x); f1.y = fmaf(a.y, xv.y, f1.y);
      f1.z = fmaf(a.y, xv.z, f1.z); f1.w = fmaf(a.y, xv.w, f1.w);
    }
    float4* pc4 = reinterpret_cast<float4*>(pcbuf);
    pc4[jp * 64 + 0 * 32 + dg] = f0;   // pcbuf[jp*256 + r*128 + dg*4..]
    pc4[jp * 64 + 1 * 32 + dg] = f1;
  }
  __syncthreads();
  // reduce 16 partials -> hsT[r*128+e]
  if (t < 256) {
    float v = 0.f;
#pragma unroll
    for (int jp = 0; jp < 16; ++jp) v += pcbuf[jp * 256 + t];
    hsT[t] = v;   // t = r*128 + e
  }
  __syncthreads();

  // ---- Phase D: out = h_out @ Wp + bp ----
  {
    const int d = t & 127, eh = t >> 7;   // 4 e-groups of 32 e's
    float a0 = 0.f, a1 = 0.f;
    for (int ee = 0; ee < 32; ++ee) {
      const int e = eh * 32 + ee;
      const float w = Wp[(size_t)e * ND + d];
      a0 = fmaf(hsT[0 * 128 + e], w, a0);
      a1 = fmaf(hsT[1 * 128 + e], w, a1);
    }
    float* pd = pcbuf;   // reuse (barrier passed since last read)
    pd[eh * 256 + 0 * 128 + d] = a0;
    pd[eh * 256 + 1 * 128 + d] = a1;
  }
  __syncthreads();
  if (t < 256) {
    const float* pd = pcbuf;
    const int r = t >> 7, d = t & 127;
    const float v = pd[0 * 256 + t] + pd[1 * 256 + t] + pd[2 * 256 + t] +
                    pd[3 * 256 + t] + bp[d];
    out[(size_t)(b * NN + i0 + r) * ND + d] = v;
  }
}

// Fallback: fused kernel (R3-verified), used if ws is too small.
__global__ __launch_bounds__(512, 4) void dgf_fused(
    const float* __restrict__ x, const float* __restrict__ W2,
    const float* __restrict__ b2, const float* __restrict__ Wp,
    const float* __restrict__ bp, const float* __restrict__ ai2,
    const float* __restrict__ aj2, const float* __restrict__ x2n,
    float* __restrict__ out) {
  __shared__ float4 xi4[4 * 32];
  __shared__ float4 ai2s4[4 * 32];
  __shared__ float4 w2s4[32];
  __shared__ float x2is[4];
  __shared__ float b2s[4];
  __shared__ float4 adjs4[512];
  __shared__ float pcbuf[16 * 512];
  __shared__ float hsT[4 * 128];
  const int t = threadIdx.x;
  const int blk = blockIdx.x;
  const int b = blk >> 7;
  const int i0 = (blk & 127) << 2;

  if (t < 128) {
    const int r = t >> 5;
    const int c = t & 31;
    xi4[t]   = ld4(x   + (size_t)(b * NN + i0 + r) * ND + c * 4);
    ai2s4[t] = ld4(ai2 + (size_t)(b * NN + i0 + r) * (NH * NK) + c * 4);
  } else if (t < 160) {
    const float4 w = ld4(W2 + (t - 128) * 4);
    float4 wn;
    wn.x = -2.f * w.x; wn.y = -2.f * w.y; wn.z = -2.f * w.z; wn.w = -2.f * w.w;
    w2s4[t - 128] = wn;
  } else if (t < 164) {
    x2is[t - 160] = x2n[b * NN + i0 + (t - 160)];
  } else if (t < 168) {
    const int h = t - 164;
    float sw = 0.f;
    for (int k = 0; k < NK; ++k) sw += W2[h * NK + k];
    b2s[h] = b2[h] + sw;
  }
  __syncthreads();

  float dn[4];
  {
    float g[4] = {0.f, 0.f, 0.f, 0.f};
    const float* xj = x + (size_t)(b * NN + t) * ND;
    for (int c = 0; c < 32; ++c) {
      const float4 a = ld4(xj + c * 4);
#pragma unroll
      for (int r = 0; r < 4; ++r) {
        const float4 xv = xi4[r * 32 + c];
        float u = g[r];
        u = fmaf(xv.x, a.x, u); u = fmaf(xv.y, a.y, u);
        u = fmaf(xv.z, a.z, u); u = fmaf(xv.w, a.w, u);
        g[r] = u;
      }
    }
    const float x2j = x2n[b * NN + t];
#pragma unroll
    for (int r = 0; r < 4; ++r)
      dn[r] = -L2E * fmaxf(x2is[r] + x2j - 2.f * g[r], 0.f);
  }

  float adjv[4] = {0.f, 0.f, 0.f, 0.f};
  {
    const float* ajp = aj2 + (size_t)(b * NN + t) * (NH * NK);
    for (int h = 0; h < NH; ++h) {
      float4 aj[8];
#pragma unroll
      for (int c = 0; c < 8; ++c) aj[c] = ld4(ajp + h * NK + c * 4);
      float s[4] = {0.f, 0.f, 0.f, 0.f};
#pragma unroll
      for (int kc = 0; kc < 8; ++kc) {
        const float4 w2c = w2s4[h * 8 + kc];
        const float4 ajc = aj[kc];
#pragma unroll
        for (int r = 0; r < 4; ++r) {
          const float4 ac = ai2s4[r * 32 + h * 8 + kc];
          float z, rc, sr = s[r];
          z = ac.x + ajc.x;
          rc = __builtin_amdgcn_rcpf(__builtin_amdgcn_exp2f(z) + 1.f);
          sr = fmaf(w2c.x, rc, sr);
          z = ac.y + ajc.y;
          rc = __builtin_amdgcn_rcpf(__builtin_amdgcn_exp2f(z) + 1.f);
          sr = fmaf(w2c.y, rc, sr);
          z = ac.z + ajc.z;
          rc = __builtin_amdgcn_rcpf(__builtin_amdgcn_exp2f(z) + 1.f);
          sr = fmaf(w2c.z, rc, sr);
          z = ac.w + ajc.w;
          rc = __builtin_amdgcn_rcpf(__builtin_amdgcn_exp2f(z) + 1.f);
          sr = fmaf(w2c.w, rc, sr);
          s[r] = sr;
        }
      }
#pragma unroll
      for (int r = 0; r < 4; ++r) {
        const float si = s[r] + b2s[h];
        const float e2 = __builtin_amdgcn_exp2f(si * L2E);
        const float lp = __builtin_amdgcn_logf(e2 + 1.f) * LN2V;
        const float sp = (si > 15.f) ? si : lp;
        const float den = fmaf(2.f * sp, sp, EPSV);
        const float rr = __builtin_amdgcn_rcpf(den);
        adjv[r] += __builtin_amdgcn_exp2f(dn[r] * rr);
      }
    }
  }
  {
    float4 v;
    v.x = adjv[0] * 0.25f; v.y = adjv[1] * 0.25f;
    v.z = adjv[2] * 0.25f; v.w = adjv[3] * 0.25f;
    adjs4[t] = v;
  }
  __syncthreads();

  {
    const int dg = t & 31, jp = t >> 5;
    float4 f0 = {0,0,0,0}, f1 = {0,0,0,0}, f2 = {0,0,0,0}, f3 = {0,0,0,0};
    const float* xb = x + (size_t)(b * NN) * ND;
    for (int u = 0; u < 32; ++u) {
      const int j = jp * 32 + u;
      const float4 a = adjs4[j];
      const float4 xv = ld4(xb + (size_t)j * ND + dg * 4);
      f0.x = fmaf(a.x, xv.x, f0.x); f0.y = fmaf(a.x, xv.y, f0.y);
      f0.z = fmaf(a.x, xv.z, f0.z); f0.w = fmaf(a.x, xv.w, f0.w);
      f1.x = fmaf(a.y, xv.x, f1.x); f1.y = fmaf(a.y, xv.y, f1.y);
      f1.z = fmaf(a.y, xv.z, f1.z); f1.w = fmaf(a.y, xv.w, f1.w);
      f2.x = fmaf(a.z, xv.x, f2.x); f2.y = fmaf(a.z, xv.y, f2.y);
      f2.z = fmaf(a.z, xv.z, f2.z); f2.w = fmaf(a.z, xv.w, f2.w);
      f3.x = fmaf(a.w, xv.x, f3.x); f3.y = fmaf(a.w, xv.y, f3.y);
      f3.z = fmaf(a.w, xv.z, f3.z); f3.w = fmaf(a.w, xv.w, f3.w);
    }
    float4* pc4 = reinterpret_cast<float4*>(pcbuf);
    pc4[jp * 128 + 0 * 32 + dg] = f0;
    pc4[jp * 128 + 1 * 32 + dg] = f1;
    pc4[jp * 128 + 2 * 32 + dg] = f2;
    pc4[jp * 128 + 3 * 32 + dg] = f3;
  }
  __syncthreads();
  {
    float v = 0.f;
#pragma unroll
    for (int jp = 0; jp < 16; ++jp) v += pcbuf[jp * 512 + t];
    hsT[t] = v;
  }
  __syncthreads();
  {
    const int d = t & 127, eh = t >> 7;
    float a0 = 0.f, a1 = 0.f, a2 = 0.f, a3 = 0.f;
    for (int ee = 0; ee < 32; ++ee) {
      const int e = eh * 32 + ee;
      const float w = Wp[(size_t)e * ND + d];
      a0 = fmaf(hsT[0 * 128 + e], w, a0);
      a1 = fmaf(hsT[1 * 128 + e], w, a1);
      a2 = fmaf(hsT[2 * 128 + e], w, a2);
      a3 = fmaf(hsT[3 * 128 + e], w, a3);
    }
    float* pd = pcbuf;
    pd[eh * 512 + 0 * 128 + d] = a0;
    pd[eh * 512 + 1 * 128 + d] = a1;
    pd[eh * 512 + 2 * 128 + d] = a2;
    pd[eh * 512 + 3 * 128 + d] = a3;
  }
  __syncthreads();
  {
    const int d = t & 127;
    const float v = pcbuf[0 * 512 + t] + pcbuf[1 * 512 + t] +
                    pcbuf[2 * 512 + t] + pcbuf[3 * 512 + t] + bp[d];
    const int r = t >> 7;
    out[(size_t)(b * NN + i0 + r) * ND + d] = v;
  }
}

extern "C" void kernel_launch(void* const* d_in, const int* in_sizes, int n_in,
                              void* d_out, int out_size, void* d_ws, size_t ws_size,
                              hipStream_t stream) {
  const float* x  = (const float*)d_in[0];
  const float* W1 = (const float*)d_in[1];
  const float* b1 = (const float*)d_in[2];
  const float* W2 = (const float*)d_in[3];
  const float* b2 = (const float*)d_in[4];
  const float* Wp = (const float*)d_in[5];
  const float* bp = (const float*)d_in[6];
  float* out = (float*)d_out;

  const size_t nProj = (size_t)NB * NN * NH * NK;   // 262144
  const size_t nX2   = (size_t)NB * NN;             // 2048
  const size_t nDist = (size_t)NB * NN * NN;        // 1048576

  float* aj2 = (float*)d_ws;
  float* ai2 = aj2 + nProj;
  float* x2n = ai2 + nProj;
  float* dnt = x2n + nX2;           // 4 floats (1 used)
  float* dst = dnt + 4;

  dgf_proj<<<NB * NN / 8, 256, 0, stream>>>(x, W1, b1, W2, b2, ai2, aj2, x2n,
                                            dnt);

  if (ws_size >= (2 * nProj + nX2 + 4 + nDist) * sizeof(float)) {
    dgf_dist<<<NB * (NN / 8) * 2, 256, 0, stream>>>(x, x2n, dst);
    dgf_adj<<<NB * (NN / 2), 512, 0, stream>>>(x, W2, b2, Wp, bp, ai2, aj2,
                                               dst, out);
  } else {
    dgf_fused<<<NB * (NN / 4), 512, 0, stream>>>(x, W2, b2, Wp, bp, ai2, aj2,
                                                 x2n, out);
  }
}

// Round 15
// 41.396 us; speedup vs baseline: 1.4039x; 1.2578x over previous
//
#include <hip/hip_runtime.h>
#include <hip/hip_bf16.h>

#define NB 4
#define NN 512
#define ND 128
#define NH 4
#define NK 32

constexpr float EPSV = 1e-6f;
constexpr float CF   = 2.8853900817779268f;   // 2/ln2
constexpr float L2E  = 1.4426950408889634f;   // log2(e)
constexpr float LN2V = 0.6931471805599453f;   // ln(2)
constexpr float EXPCUT = 25.0f;               // skip terms < e^-25 (rigorous bound)

__device__ __forceinline__ float4 ld4(const float* __restrict__ p) {
  return *reinterpret_cast<const float4*>(p);
}

// Kernel 1 (merged): blocks 0..255 = proj; blocks 256..767 = dist.
// proj: ai' = (x@W1a + b1)*CF, aj' = (x@W1b)*CF, x2n; block 0 computes dnth.
// dist: distn[b][i][j] = -L2E * max(x2i + x2j - 2*<xi,xj>, 0), x2 inline
//       (no dependency on proj -> both halves run concurrently).
__global__ __launch_bounds__(256) void dgf_prep(
    const float* __restrict__ x, const float* __restrict__ W1,
    const float* __restrict__ b1, const float* __restrict__ W2,
    const float* __restrict__ b2, float* __restrict__ ai2,
    float* __restrict__ aj2, float* __restrict__ x2n,
    float* __restrict__ dnthp, float* __restrict__ distn) {
  const int t = threadIdx.x;
  const int gblk = blockIdx.x;

  if (gblk < 256) {
    // ---------------- proj ----------------
    __shared__ float xr[8][ND];
    const int blk = gblk;
    const int b = blk >> 6;
    const int n0 = (blk & 63) << 3;
    const float* xb = x + (size_t)(b * NN + n0) * ND;
    {
      const int row = t >> 5, c = t & 31;
      *reinterpret_cast<float4*>(&xr[row][c * 4]) = ld4(xb + row * ND + c * 4);
    }
    if (blk == 0 && t == 0) {
      // sigma <= softplus(max_h(b2 + sum_k |W2|)); terms with
      // dist > EXPCUT*(2*sigmax^2+eps) are <= e^-EXPCUT -> skippable.
      float m = -1e30f;
      for (int h = 0; h < NH; ++h) {
        float sa = b2[h];
        for (int k = 0; k < NK; ++k) sa += fabsf(W2[h * NK + k]);
        m = fmaxf(m, sa);
      }
      const float e2 = __builtin_amdgcn_exp2f(m * L2E);
      const float lp = __builtin_amdgcn_logf(e2 + 1.f) * LN2V;
      const float sm = (m > 15.f) ? m : lp;          // softplus(m)
      dnthp[0] = -L2E * EXPCUT * fmaf(2.f * sm, sm, EPSV);
    }
    __syncthreads();
    if (t < 8) {
      float s = 0.f;
      for (int d = 0; d < ND; ++d) s = fmaf(xr[t][d], xr[t][d], s);
      x2n[b * NN + n0 + t] = s;
    }
    const int h = t >> 6, part = (t >> 5) & 1, k = t & 31;
    const float* w1p = W1 + (size_t)(h * 256 + part * 128) * NK + k;
    float acc[8] = {0.f, 0.f, 0.f, 0.f, 0.f, 0.f, 0.f, 0.f};
    for (int d = 0; d < ND; d += 4) {
      const float w0 = w1p[(d + 0) * NK];
      const float w1v = w1p[(d + 1) * NK];
      const float w2v = w1p[(d + 2) * NK];
      const float w3v = w1p[(d + 3) * NK];
#pragma unroll
      for (int row = 0; row < 8; ++row) {
        const float4 xv = *reinterpret_cast<const float4*>(&xr[row][d]);
        float a = acc[row];
        a = fmaf(xv.x, w0, a);
        a = fmaf(xv.y, w1v, a);
        a = fmaf(xv.z, w2v, a);
        a = fmaf(xv.w, w3v, a);
        acc[row] = a;
      }
    }
    const float bb = (part == 0) ? b1[h * NK + k] : 0.f;
    float* outp = (part == 0) ? ai2 : aj2;
#pragma unroll
    for (int row = 0; row < 8; ++row) {
      outp[((size_t)(b * NN + n0 + row) * NH + h) * NK + k] =
          (acc[row] + bb) * CF;
    }
  } else {
    // ---------------- dist (x2 computed inline) ----------------
    __shared__ float4 xi4s[8 * 32];   // 8 i-rows   4KB
    __shared__ float x2is[8];
    const int blk = gblk - 256;
    const int xcd = blk & 7;
    const int idx = blk >> 3;
    const int b = xcd >> 1;
    const int igrp = ((xcd & 1) << 5) + (idx >> 1);
    const int jh = idx & 1;
    const int i0 = igrp << 3;
    const int j = (jh << 8) + t;

    {
      const int row = t >> 5, c = t & 31;
      xi4s[t] = ld4(x + (size_t)(b * NN + i0 + row) * ND + c * 4);
    }
    __syncthreads();
    if (t < 8) {
      float s = 0.f;
#pragma unroll
      for (int c = 0; c < 32; ++c) {
        const float4 v = xi4s[t * 32 + c];
        s = fmaf(v.x, v.x, s); s = fmaf(v.y, v.y, s);
        s = fmaf(v.z, v.z, s); s = fmaf(v.w, v.w, s);
      }
      x2is[t] = s;
    }

    float g[8] = {0.f, 0.f, 0.f, 0.f, 0.f, 0.f, 0.f, 0.f};
    float x2j = 0.f;
    const float* xj = x + (size_t)(b * NN + j) * ND;
    for (int c = 0; c < 32; ++c) {
      const float4 a = ld4(xj + c * 4);
      x2j = fmaf(a.x, a.x, x2j); x2j = fmaf(a.y, a.y, x2j);
      x2j = fmaf(a.z, a.z, x2j); x2j = fmaf(a.w, a.w, x2j);
#pragma unroll
      for (int r = 0; r < 8; ++r) {
        const float4 xv = xi4s[r * 32 + c];
        float u = g[r];
        u = fmaf(xv.x, a.x, u); u = fmaf(xv.y, a.y, u);
        u = fmaf(xv.z, a.z, u); u = fmaf(xv.w, a.w, u);
        g[r] = u;
      }
    }
    __syncthreads();   // x2is visible
    float* dp = distn + (size_t)b * NN * NN + (size_t)i0 * NN + j;
#pragma unroll
    for (int r = 0; r < 8; ++r) {
      dp[(size_t)r * NN] = -L2E * fmaxf(x2is[r] + x2j - 2.f * g[r], 0.f);
    }
  }
}

// Kernel 2: B2 (heads, wave-skip) + C (adj@x, GROUP-SKIPPED via ballot
// flags) + D (proj). i-tile = 2, grid = B*(N/2) = 1024 blocks.
// XCD mapping as R14: xcd=blk&7 -> b=xcd>>1, hi=xcd&1.
__global__ __launch_bounds__(512, 4) void dgf_adj(
    const float* __restrict__ x, const float* __restrict__ W2,
    const float* __restrict__ b2, const float* __restrict__ Wp,
    const float* __restrict__ bp, const float* __restrict__ ai2,
    const float* __restrict__ aj2, const float* __restrict__ distn,
    const float* __restrict__ dnthp, float* __restrict__ out) {
  __shared__ float4 ai2s4[2 * 32];   // 2 i-rows of ai'  1KB
  __shared__ float4 w2s4[32];        // -2*W2 [h][k]     0.5KB
  __shared__ float b2s[4];           // b2[h] + sum_k W2[h][k]
  __shared__ float dnths;            // skip threshold in dn units
  __shared__ float cflag[16];        // per 32-j-group hotness (Phase C skip)
  __shared__ float2 adjs2[512];      // [j] -> (r0, r1)  4KB
  __shared__ float pcbuf[16 * 256];  // 16KB: C partials; reused as pd in D
  __shared__ float hsT[2 * 128];     // [r][e]  1KB
  const int t = threadIdx.x;
  const int blk = blockIdx.x;
  const int xcd = blk & 7;
  const int b = xcd >> 1;
  const int i0 = (((xcd & 1) << 7) + (blk >> 3)) << 1;

  // ---- Phase A ----
  if (t < 64) {
    const int r = t >> 5;
    const int c = t & 31;
    ai2s4[t] = ld4(ai2 + (size_t)(b * NN + i0 + r) * (NH * NK) + c * 4);
  } else if (t < 96) {
    const float4 w = ld4(W2 + (t - 64) * 4);
    float4 wn;
    wn.x = -2.f * w.x; wn.y = -2.f * w.y; wn.z = -2.f * w.z; wn.w = -2.f * w.w;
    w2s4[t - 64] = wn;
  } else if (t < 100) {
    const int h = t - 96;
    float sw = 0.f;
    for (int k = 0; k < NK; ++k) sw += W2[h * NK + k];
    b2s[h] = b2[h] + sw;
  } else if (t == 100) {
    dnths = dnthp[0];
  }
  __syncthreads();

  // ---- distn loads ----
  float dn[2];
  {
    const float* dp = distn + (size_t)b * NN * NN + (size_t)i0 * NN + t;
    dn[0] = dp[0];
    dn[1] = dp[NN];
  }

  // ---- Phase B2 (wave-skippable) ----
  float adjv[2] = {0.f, 0.f};
  {
    const float dnth = dnths;
    const bool need = (dn[0] > dnth) || (dn[1] > dnth);
    const unsigned long long bm = __ballot(need);
    if ((t & 63) == 0) {
      const int w = t >> 6;
      cflag[2 * w]     = (bm & 0xffffffffULL) ? 1.f : 0.f;
      cflag[2 * w + 1] = (bm >> 32) ? 1.f : 0.f;
    }
    if (__any(need)) {
      const float* ajp = aj2 + (size_t)(b * NN + t) * (NH * NK);
      for (int h = 0; h < NH; ++h) {
        float4 aj[8];
#pragma unroll
        for (int c = 0; c < 8; ++c) aj[c] = ld4(ajp + h * NK + c * 4);
        float s[2] = {0.f, 0.f};
#pragma unroll
        for (int kc = 0; kc < 8; ++kc) {
          const float4 w2c = w2s4[h * 8 + kc];   // already -2*W2
          const float4 ajc = aj[kc];
#pragma unroll
          for (int r = 0; r < 2; ++r) {
            const float4 ac = ai2s4[r * 32 + h * 8 + kc];
            float z, rc, sr = s[r];
            z = ac.x + ajc.x;
            rc = __builtin_amdgcn_rcpf(__builtin_amdgcn_exp2f(z) + 1.f);
            sr = fmaf(w2c.x, rc, sr);
            z = ac.y + ajc.y;
            rc = __builtin_amdgcn_rcpf(__builtin_amdgcn_exp2f(z) + 1.f);
            sr = fmaf(w2c.y, rc, sr);
            z = ac.z + ajc.z;
            rc = __builtin_amdgcn_rcpf(__builtin_amdgcn_exp2f(z) + 1.f);
            sr = fmaf(w2c.z, rc, sr);
            z = ac.w + ajc.w;
            rc = __builtin_amdgcn_rcpf(__builtin_amdgcn_exp2f(z) + 1.f);
            sr = fmaf(w2c.w, rc, sr);
            s[r] = sr;
          }
        }
#pragma unroll
        for (int r = 0; r < 2; ++r) {
          const float si = s[r] + b2s[h];       // + (b2 + sum_k W2)
          const float e2 = __builtin_amdgcn_exp2f(si * L2E);
          const float lp = __builtin_amdgcn_logf(e2 + 1.f) * LN2V;
          const float sp = (si > 15.f) ? si : lp;   // softplus
          const float den = fmaf(2.f * sp, sp, EPSV);
          const float rr = __builtin_amdgcn_rcpf(den);
          adjv[r] += __builtin_amdgcn_exp2f(dn[r] * rr);
        }
      }
    }
  }
  {
    float2 v;
    v.x = adjv[0] * 0.25f;
    v.y = adjv[1] * 0.25f;
    adjs2[t] = v;
  }
  __syncthreads();

  // ---- Phase C: h_out = adj @ x, skipping cold 32-j groups ----
  {
    const int dg = t & 31, jp = t >> 5;   // 16 j-groups of 32 j's
    float4 f0 = {0, 0, 0, 0}, f1 = {0, 0, 0, 0};
    if (cflag[jp] != 0.f) {
      const float* xb = x + (size_t)(b * NN) * ND;
      for (int u = 0; u < 32; ++u) {
        const int j = jp * 32 + u;
        const float2 a = adjs2[j];
        const float4 xv = ld4(xb + (size_t)j * ND + dg * 4);
        f0.x = fmaf(a.x, xv.x, f0.x); f0.y = fmaf(a.x, xv.y, f0.y);
        f0.z = fmaf(a.x, xv.z, f0.z); f0.w = fmaf(a.x, xv.w, f0.w);
        f1.x = fmaf(a.y, xv.x, f1.x); f1.y = fmaf(a.y, xv.y, f1.y);
        f1.z = fmaf(a.y, xv.z, f1.z); f1.w = fmaf(a.y, xv.w, f1.w);
      }
    }
    float4* pc4 = reinterpret_cast<float4*>(pcbuf);
    pc4[jp * 64 + 0 * 32 + dg] = f0;   // pcbuf[jp*256 + r*128 + dg*4..]
    pc4[jp * 64 + 1 * 32 + dg] = f1;
  }
  __syncthreads();
  // reduce 16 partials -> hsT[r*128+e]
  if (t < 256) {
    float v = 0.f;
#pragma unroll
    for (int jp = 0; jp < 16; ++jp) v += pcbuf[jp * 256 + t];
    hsT[t] = v;   // t = r*128 + e
  }
  __syncthreads();

  // ---- Phase D: out = h_out @ Wp + bp ----
  {
    const int d = t & 127, eh = t >> 7;   // 4 e-groups of 32 e's
    float a0 = 0.f, a1 = 0.f;
    for (int ee = 0; ee < 32; ++ee) {
      const int e = eh * 32 + ee;
      const float w = Wp[(size_t)e * ND + d];
      a0 = fmaf(hsT[0 * 128 + e], w, a0);
      a1 = fmaf(hsT[1 * 128 + e], w, a1);
    }
    float* pd = pcbuf;   // reuse (barrier passed since last read)
    pd[eh * 256 + 0 * 128 + d] = a0;
    pd[eh * 256 + 1 * 128 + d] = a1;
  }
  __syncthreads();
  if (t < 256) {
    const float* pd = pcbuf;
    const int r = t >> 7, d = t & 127;
    const float v = pd[0 * 256 + t] + pd[1 * 256 + t] + pd[2 * 256 + t] +
                    pd[3 * 256 + t] + bp[d];
    out[(size_t)(b * NN + i0 + r) * ND + d] = v;
  }
}

// Fallback: fused kernel (R3-verified), used if ws is too small.
__global__ __launch_bounds__(512, 4) void dgf_fused(
    const float* __restrict__ x, const float* __restrict__ W2,
    const float* __restrict__ b2, const float* __restrict__ Wp,
    const float* __restrict__ bp, const float* __restrict__ ai2,
    const float* __restrict__ aj2, const float* __restrict__ x2n,
    float* __restrict__ out) {
  __shared__ float4 xi4[4 * 32];
  __shared__ float4 ai2s4[4 * 32];
  __shared__ float4 w2s4[32];
  __shared__ float x2is[4];
  __shared__ float b2s[4];
  __shared__ float4 adjs4[512];
  __shared__ float pcbuf[16 * 512];
  __shared__ float hsT[4 * 128];
  const int t = threadIdx.x;
  const int blk = blockIdx.x;
  const int b = blk >> 7;
  const int i0 = (blk & 127) << 2;

  if (t < 128) {
    const int r = t >> 5;
    const int c = t & 31;
    xi4[t]   = ld4(x   + (size_t)(b * NN + i0 + r) * ND + c * 4);
    ai2s4[t] = ld4(ai2 + (size_t)(b * NN + i0 + r) * (NH * NK) + c * 4);
  } else if (t < 160) {
    const float4 w = ld4(W2 + (t - 128) * 4);
    float4 wn;
    wn.x = -2.f * w.x; wn.y = -2.f * w.y; wn.z = -2.f * w.z; wn.w = -2.f * w.w;
    w2s4[t - 128] = wn;
  } else if (t < 164) {
    x2is[t - 160] = x2n[b * NN + i0 + (t - 160)];
  } else if (t < 168) {
    const int h = t - 164;
    float sw = 0.f;
    for (int k = 0; k < NK; ++k) sw += W2[h * NK + k];
    b2s[h] = b2[h] + sw;
  }
  __syncthreads();

  float dn[4];
  {
    float g[4] = {0.f, 0.f, 0.f, 0.f};
    const float* xj = x + (size_t)(b * NN + t) * ND;
    for (int c = 0; c < 32; ++c) {
      const float4 a = ld4(xj + c * 4);
#pragma unroll
      for (int r = 0; r < 4; ++r) {
        const float4 xv = xi4[r * 32 + c];
        float u = g[r];
        u = fmaf(xv.x, a.x, u); u = fmaf(xv.y, a.y, u);
        u = fmaf(xv.z, a.z, u); u = fmaf(xv.w, a.w, u);
        g[r] = u;
      }
    }
    const float x2j = x2n[b * NN + t];
#pragma unroll
    for (int r = 0; r < 4; ++r)
      dn[r] = -L2E * fmaxf(x2is[r] + x2j - 2.f * g[r], 0.f);
  }

  float adjv[4] = {0.f, 0.f, 0.f, 0.f};
  {
    const float* ajp = aj2 + (size_t)(b * NN + t) * (NH * NK);
    for (int h = 0; h < NH; ++h) {
      float4 aj[8];
#pragma unroll
      for (int c = 0; c < 8; ++c) aj[c] = ld4(ajp + h * NK + c * 4);
      float s[4] = {0.f, 0.f, 0.f, 0.f};
#pragma unroll
      for (int kc = 0; kc < 8; ++kc) {
        const float4 w2c = w2s4[h * 8 + kc];
        const float4 ajc = aj[kc];
#pragma unroll
        for (int r = 0; r < 4; ++r) {
          const float4 ac = ai2s4[r * 32 + h * 8 + kc];
          float z, rc, sr = s[r];
          z = ac.x + ajc.x;
          rc = __builtin_amdgcn_rcpf(__builtin_amdgcn_exp2f(z) + 1.f);
          sr = fmaf(w2c.x, rc, sr);
          z = ac.y + ajc.y;
          rc = __builtin_amdgcn_rcpf(__builtin_amdgcn_exp2f(z) + 1.f);
          sr = fmaf(w2c.y, rc, sr);
          z = ac.z + ajc.z;
          rc = __builtin_amdgcn_rcpf(__builtin_amdgcn_exp2f(z) + 1.f);
          sr = fmaf(w2c.z, rc, sr);
          z = ac.w + ajc.w;
          rc = __builtin_amdgcn_rcpf(__builtin_amdgcn_exp2f(z) + 1.f);
          sr = fmaf(w2c.w, rc, sr);
          s[r] = sr;
        }
      }
#pragma unroll
      for (int r = 0; r < 4; ++r) {
        const float si = s[r] + b2s[h];
        const float e2 = __builtin_amdgcn_exp2f(si * L2E);
        const float lp = __builtin_amdgcn_logf(e2 + 1.f) * LN2V;
        const float sp = (si > 15.f) ? si : lp;
        const float den = fmaf(2.f * sp, sp, EPSV);
        const float rr = __builtin_amdgcn_rcpf(den);
        adjv[r] += __builtin_amdgcn_exp2f(dn[r] * rr);
      }
    }
  }
  {
    float4 v;
    v.x = adjv[0] * 0.25f; v.y = adjv[1] * 0.25f;
    v.z = adjv[2] * 0.25f; v.w = adjv[3] * 0.25f;
    adjs4[t] = v;
  }
  __syncthreads();

  {
    const int dg = t & 31, jp = t >> 5;
    float4 f0 = {0,0,0,0}, f1 = {0,0,0,0}, f2 = {0,0,0,0}, f3 = {0,0,0,0};
    const float* xb = x + (size_t)(b * NN) * ND;
    for (int u = 0; u < 32; ++u) {
      const int j = jp * 32 + u;
      const float4 a = adjs4[j];
      const float4 xv = ld4(xb + (size_t)j * ND + dg * 4);
      f0.x = fmaf(a.x, xv.x, f0.x); f0.y = fmaf(a.x, xv.y, f0.y);
      f0.z = fmaf(a.x, xv.z, f0.z); f0.w = fmaf(a.x, xv.w, f0.w);
      f1.x = fmaf(a.y, xv.x, f1.x); f1.y = fmaf(a.y, xv.y, f1.y);
      f1.z = fmaf(a.y, xv.z, f1.z); f1.w = fmaf(a.y, xv.w, f1.w);
      f2.x = fmaf(a.z, xv.x, f2.x); f2.y = fmaf(a.z, xv.y, f2.y);
      f2.z = fmaf(a.z, xv.z, f2.z); f2.w = fmaf(a.z, xv.w, f2.w);
      f3.x = fmaf(a.w, xv.x, f3.x); f3.y = fmaf(a.w, xv.y, f3.y);
      f3.z = fmaf(a.w, xv.z, f3.z); f3.w = fmaf(a.w, xv.w, f3.w);
    }
    float4* pc4 = reinterpret_cast<float4*>(pcbuf);
    pc4[jp * 128 + 0 * 32 + dg] = f0;
    pc4[jp * 128 + 1 * 32 + dg] = f1;
    pc4[jp * 128 + 2 * 32 + dg] = f2;
    pc4[jp * 128 + 3 * 32 + dg] = f3;
  }
  __syncthreads();
  {
    float v = 0.f;
#pragma unroll
    for (int jp = 0; jp < 16; ++jp) v += pcbuf[jp * 512 + t];
    hsT[t] = v;
  }
  __syncthreads();
  {
    const int d = t & 127, eh = t >> 7;
    float a0 = 0.f, a1 = 0.f, a2 = 0.f, a3 = 0.f;
    for (int ee = 0; ee < 32; ++ee) {
      const int e = eh * 32 + ee;
      const float w = Wp[(size_t)e * ND + d];
      a0 = fmaf(hsT[0 * 128 + e], w, a0);
      a1 = fmaf(hsT[1 * 128 + e], w, a1);
      a2 = fmaf(hsT[2 * 128 + e], w, a2);
      a3 = fmaf(hsT[3 * 128 + e], w, a3);
    }
    float* pd = pcbuf;
    pd[eh * 512 + 0 * 128 + d] = a0;
    pd[eh * 512 + 1 * 128 + d] = a1;
    pd[eh * 512 + 2 * 128 + d] = a2;
    pd[eh * 512 + 3 * 128 + d] = a3;
  }
  __syncthreads();
  {
    const int d = t & 127;
    const float v = pcbuf[0 * 512 + t] + pcbuf[1 * 512 + t] +
                    pcbuf[2 * 512 + t] + pcbuf[3 * 512 + t] + bp[d];
    const int r = t >> 7;
    out[(size_t)(b * NN + i0 + r) * ND + d] = v;
  }
}

extern "C" void kernel_launch(void* const* d_in, const int* in_sizes, int n_in,
                              void* d_out, int out_size, void* d_ws, size_t ws_size,
                              hipStream_t stream) {
  const float* x  = (const float*)d_in[0];
  const float* W1 = (const float*)d_in[1];
  const float* b1 = (const float*)d_in[2];
  const float* W2 = (const float*)d_in[3];
  const float* b2 = (const float*)d_in[4];
  const float* Wp = (const float*)d_in[5];
  const float* bp = (const float*)d_in[6];
  float* out = (float*)d_out;

  const size_t nProj = (size_t)NB * NN * NH * NK;   // 262144
  const size_t nX2   = (size_t)NB * NN;             // 2048
  const size_t nDist = (size_t)NB * NN * NN;        // 1048576

  float* aj2 = (float*)d_ws;
  float* ai2 = aj2 + nProj;
  float* x2n = ai2 + nProj;
  float* dnt = x2n + nX2;           // 4 floats (1 used)
  float* dst = dnt + 4;

  if (ws_size >= (2 * nProj + nX2 + 4 + nDist) * sizeof(float)) {
    dgf_prep<<<256 + NB * (NN / 8) * 2, 256, 0, stream>>>(
        x, W1, b1, W2, b2, ai2, aj2, x2n, dnt, dst);
    dgf_adj<<<NB * (NN / 2), 512, 0, stream>>>(x, W2, b2, Wp, bp, ai2, aj2,
                                               dst, dnt, out);
  } else {
    dgf_prep<<<256, 256, 0, stream>>>(x, W1, b1, W2, b2, ai2, aj2, x2n, dnt,
                                      dst);
    dgf_fused<<<NB * (NN / 4), 512, 0, stream>>>(x, W2, b2, Wp, bp, ai2, aj2,
                                                 x2n, out);
  }
}